// Round 2
// baseline (424.751 us; speedup 1.0000x reference)
//
#include <hip/hip_runtime.h>
#include <stdint.h>

#define BB 8
#define II 64
#define OO 64
#define NN 8192
#define KK 16
#define DD 3
#define H1C 16
#define H2C 32

typedef __attribute__((ext_vector_type(8))) short short8;
typedef __attribute__((ext_vector_type(4))) float f32x4;
typedef __attribute__((ext_vector_type(4))) unsigned int uint4v;
typedef __attribute__((ext_vector_type(2))) unsigned int uint2v;

__device__ __forceinline__ unsigned short f2bf(float f) {
    unsigned int u = __float_as_uint(f);
    u += 0x7fffu + ((u >> 16) & 1u);   // RNE
    return (unsigned short)(u >> 16);
}
__device__ __forceinline__ unsigned pack2(float a, float b) {
    return (unsigned)f2bf(a) | ((unsigned)f2bf(b) << 16);
}

// One wave processes 16 consecutive n for one b. Per (b,n):
//   stage1 (3->16) on VALU (lane: point k=lane&15, feats m=4g+r)
//   stage2 (16->32) as h2^T = W2^T @ h1^T   (1 padded K, 2 MFMA)
//   h2 via wave-private swizzled LDS -> stage3 A-frag
//   stage3 (32->64) mat = h2 @ W3           (4 MFMA)
//   feats  = input_slice^T @ weight          (8 MFMA, A direct from global)
//   out[o] = sum_k feats[k][o]*mat[k][o]  (in-lane FMA + xor16/32 reduce)
__global__ void __launch_bounds__(256) pccn_fused(
    const float* __restrict__ input, const float* __restrict__ points,
    const float* __restrict__ support, const float* __restrict__ weight,
    const float* __restrict__ bias, const float* __restrict__ W1,
    const float* __restrict__ b1, const float* __restrict__ W2,
    const float* __restrict__ b2, const float* __restrict__ W3,
    const float* __restrict__ b3, float* __restrict__ out)
{
    __shared__ __align__(16) unsigned char lds[4 * 1024];  // 1 KB per wave (h2 tile)

    const int tid  = threadIdx.x;
    const int wid  = tid >> 6;
    const int lane = tid & 63;
    const int g    = lane >> 4;
    const int q    = lane & 15;

    const int W  = blockIdx.x * 4 + wid;   // 4096 waves total
    const int b  = W >> 9;                 // 512 waves per batch
    const int n0 = (W & 511) * 16;

    // ---------------- preload weight fragments (one-time) ----------------
    float w1x[4], w1y[4], w1z[4], b1v[4];
#pragma unroll
    for (int r = 0; r < 4; ++r) {
        int m = 4 * g + r;
        w1x[r] = W1[0 * H1C + m];
        w1y[r] = W1[1 * H1C + m];
        w1z[r] = W1[2 * H1C + m];
        b1v[r] = b1[m];
    }

    // stage2 A-frag: A[row=h2dim=q+16t][kk=8g+j] = W2[kk][h2dim] (kk<16 real)
    short8 w2f[2];
#pragma unroll
    for (int t = 0; t < 2; ++t)
#pragma unroll
        for (int j = 0; j < 8; ++j) {
            int kk = 8 * g + j;
            float v = (kk < H1C) ? W2[kk * H2C + q + 16 * t] : 0.f;
            w2f[t][j] = (short)f2bf(v);
        }

    // stage3 B-frag: B[kk=8g+j][col=q+16ot] = W3[kk][o]
    short8 w3f[4];
#pragma unroll
    for (int ot = 0; ot < 4; ++ot)
#pragma unroll
        for (int j = 0; j < 8; ++j)
            w3f[ot][j] = (short)f2bf(W3[(8 * g + j) * OO + q + 16 * ot]);

    // feats B-frag: B[kk=i=32s+8g+j][col=o=q+16ot] = weight[i][o]
    short8 wff[2][4];
#pragma unroll
    for (int s = 0; s < 2; ++s)
#pragma unroll
        for (int ot = 0; ot < 4; ++ot)
#pragma unroll
            for (int j = 0; j < 8; ++j)
                wff[s][ot][j] = (short)f2bf(weight[(32 * s + 8 * g + j) * OO + q + 16 * ot]);

    f32x4 b2acc[2];
#pragma unroll
    for (int t = 0; t < 2; ++t)
#pragma unroll
        for (int r = 0; r < 4; ++r)
            b2acc[t][r] = b2[16 * t + 4 * g + r];

    float b3v[4];
#pragma unroll
    for (int ot = 0; ot < 4; ++ot) b3v[ot] = b3[q + 16 * ot];
    float biasv = bias[lane];

    // LDS addresses: h2 tile [k=q][h2dim] bf16, 64B rows, 16B chunk XOR swizzle
    const int sw = (q ^ (q >> 2)) & 3;
    const int wbase  = wid * 1024;
    const int addrw0 = wbase + q * 64 + 16 * ((((g >> 1) + 0)) ^ sw) + 8 * (g & 1); // t=0
    const int addrw1 = wbase + q * 64 + 16 * ((((g >> 1) + 2)) ^ sw) + 8 * (g & 1); // t=1
    const int addrr  = wbase + q * 64 + 16 * (g ^ sw);

    const float* inb0 = input  + (size_t)b * II * NN * KK;
    const float* ptb  = points + (size_t)b * DD * NN * KK;
    const float* spb  = support + (size_t)b * DD * NN;
    float* outb = out + (size_t)b * OO * NN;

    // per-lane constant input offsets: i = 32s+8g+j, k = q
    int ioff[16];
#pragma unroll
    for (int s = 0; s < 2; ++s)
#pragma unroll
        for (int j = 0; j < 8; ++j)
            ioff[8 * s + j] = (32 * s + 8 * g + j) * (NN * KK) + q;

    for (int nn = 0; nn < 16; ++nn) {
        const int n = n0 + nn;

        // ---- issue the 16 input dword loads early (latency overlap with MLP) ----
        const float* inbn = inb0 + n * KK;
        float fv[16];
#pragma unroll
        for (int t = 0; t < 16; ++t) fv[t] = inbn[ioff[t]];

        // ---- points / support, normalization ----
        const float* pp = (g < 3) ? (ptb + (g * NN + n) * KK + q)
                                  : (spb + (q < 3 ? q : 0) * NN + n);
        float pv = *pp;
        float sx = __shfl(pv, 48), sy = __shfl(pv, 49), sz = __shfl(pv, 50);
        float sdq = (g == 0) ? sx : ((g == 1) ? sy : sz);
        float prel = pv - sdq;                    // valid for g<3 lanes
        float ss = (g < 3) ? prel * prel : 0.f;
        ss += __shfl_xor(ss, 16);
        ss += __shfl_xor(ss, 32);                 // sq[k=q] in all lanes
        float mx = ss;
        mx = fmaxf(mx, __shfl_xor(mx, 1));
        mx = fmaxf(mx, __shfl_xor(mx, 2));
        mx = fmaxf(mx, __shfl_xor(mx, 4));
        mx = fmaxf(mx, __shfl_xor(mx, 8));
        float maxi = sqrtf(mx);
        float rn = (maxi > 0.f) ? (1.0f / maxi) : 1.0f;
        float x = __shfl(prel, q) * rn;
        float y = __shfl(prel, 16 + q) * rn;
        float z = __shfl(prel, 32 + q) * rn;

        // ---- stage1 (VALU): h1[m=4g+r] for point k=q ----
        float h1v[4];
#pragma unroll
        for (int r = 0; r < 4; ++r)
            h1v[r] = fmaxf(0.f, b1v[r] + x * w1x[r] + y * w1y[r] + z * w1z[r]);

        // redistribute h1 -> stage2 B-frag: B[kk=m=8g+j][col=k=q]
        unsigned p0 = pack2(h1v[0], h1v[1]);
        unsigned p1 = pack2(h1v[2], h1v[3]);
        int src0 = q + ((lane & 16) ? 32 : 0);
        unsigned B0 = (unsigned)__shfl((int)p0, src0);
        unsigned B1 = (unsigned)__shfl((int)p1, src0);
        unsigned B2 = (unsigned)__shfl((int)p0, src0 + 16);
        unsigned B3 = (unsigned)__shfl((int)p1, src0 + 16);
        B0 = (lane < 32) ? B0 : 0u;  // kk >= 16 is zero padding
        B1 = (lane < 32) ? B1 : 0u;
        B2 = (lane < 32) ? B2 : 0u;
        B3 = (lane < 32) ? B3 : 0u;
        union { uint4v u; short8 s; } h1f;
        h1f.u = (uint4v){B0, B1, B2, B3};

        // ---- stage2: h2^T = W2^T @ h1^T (2 MFMA) ----
        f32x4 acc20 = __builtin_amdgcn_mfma_f32_16x16x32_bf16(w2f[0], h1f.s, b2acc[0], 0, 0, 0);
        f32x4 acc21 = __builtin_amdgcn_mfma_f32_16x16x32_bf16(w2f[1], h1f.s, b2acc[1], 0, 0, 0);

        // relu, pack, wave-private LDS round trip -> stage3 A-frag
        unsigned h20 = pack2(fmaxf(0.f, acc20[0]), fmaxf(0.f, acc20[1]));
        unsigned h21 = pack2(fmaxf(0.f, acc20[2]), fmaxf(0.f, acc20[3]));
        unsigned h22 = pack2(fmaxf(0.f, acc21[0]), fmaxf(0.f, acc21[1]));
        unsigned h23 = pack2(fmaxf(0.f, acc21[2]), fmaxf(0.f, acc21[3]));
        *(uint2v*)(lds + addrw0) = (uint2v){h20, h21};
        *(uint2v*)(lds + addrw1) = (uint2v){h22, h23};
        short8 a3 = *(const short8*)(lds + addrr);  // A[row=k=q][kk=h2dim=8g+j]

        // ---- stage3: mat = h2 @ W3 + b3 (4 MFMA) ----
        f32x4 matf[4];
#pragma unroll
        for (int ot = 0; ot < 4; ++ot) {
            f32x4 c;
            c[0] = b3v[ot]; c[1] = b3v[ot]; c[2] = b3v[ot]; c[3] = b3v[ot];
            matf[ot] = __builtin_amdgcn_mfma_f32_16x16x32_bf16(a3, w3f[ot], c, 0, 0, 0);
        }

        // ---- feats = input^T @ weight (8 MFMA), A direct from global ----
        f32x4 fac[4];
#pragma unroll
        for (int ot = 0; ot < 4; ++ot) {
            fac[ot][0] = 0.f; fac[ot][1] = 0.f; fac[ot][2] = 0.f; fac[ot][3] = 0.f;
        }
#pragma unroll
        for (int s = 0; s < 2; ++s) {
            union { uint4v u; short8 s8; } af;
            af.u = (uint4v){ pack2(fv[8*s+0], fv[8*s+1]), pack2(fv[8*s+2], fv[8*s+3]),
                             pack2(fv[8*s+4], fv[8*s+5]), pack2(fv[8*s+6], fv[8*s+7]) };
#pragma unroll
            for (int ot = 0; ot < 4; ++ot)
                fac[ot] = __builtin_amdgcn_mfma_f32_16x16x32_bf16(af.s8, wff[s][ot], fac[ot], 0, 0, 0);
        }

        // ---- out[o] = sum_k feats*mat, reduce over k (rows) ----
        float part[4];
#pragma unroll
        for (int ot = 0; ot < 4; ++ot) {
            part[ot] = fac[ot][0] * matf[ot][0] + fac[ot][1] * matf[ot][1]
                     + fac[ot][2] * matf[ot][2] + fac[ot][3] * matf[ot][3];
            part[ot] += __shfl_xor(part[ot], 16);
            part[ot] += __shfl_xor(part[ot], 32);
        }
        float val = (g == 0) ? part[0] : (g == 1) ? part[1] : (g == 2) ? part[2] : part[3];
        val += biasv;
        outb[lane * NN + n] = val;   // o = lane
    }
}

extern "C" void kernel_launch(void* const* d_in, const int* in_sizes, int n_in,
                              void* d_out, int out_size, void* d_ws, size_t ws_size,
                              hipStream_t stream) {
    const float* input   = (const float*)d_in[0];
    const float* points  = (const float*)d_in[1];
    const float* support = (const float*)d_in[2];
    const float* weight  = (const float*)d_in[3];
    const float* bias    = (const float*)d_in[4];
    const float* W1      = (const float*)d_in[5];
    const float* b1      = (const float*)d_in[6];
    const float* W2      = (const float*)d_in[7];
    const float* b2      = (const float*)d_in[8];
    const float* W3      = (const float*)d_in[9];
    const float* b3      = (const float*)d_in[10];
    float* out = (float*)d_out;

    dim3 grid(1024), block(256);
    hipLaunchKernelGGL(pccn_fused, grid, block, 0, stream,
                       input, points, support, weight, bias, W1, b1, W2, b2, W3, b3, out);

    // second output: support_points passthrough
    hipMemcpyAsync(out + (size_t)BB * OO * NN, support,
                   (size_t)BB * DD * NN * sizeof(float),
                   hipMemcpyDeviceToDevice, stream);
}